// Round 3
// baseline (148.224 us; speedup 1.0000x reference)
//
#include <hip/hip_runtime.h>
#include <hip/hip_bf16.h>

// Problem constants (reference: InterpretableMultiHeadAttention)
#define NHEAD  8
#define DHEAD  64
#define HIDDEN 512
#define SEQ_T  2048
#define BATCH  4
#define NQKV   1088          // (2*8+1)*64 true width
#define QPITCH 1152          // padded to 9*128 for BN=128 GEMM tiles
#define NT     32            // 2048/64 k-tiles
#define NROWS  (BATCH * SEQ_T)   // 8192
#define NBH    (BATCH * NHEAD)   // 32
#define LPITCH (NBH * SEQ_T)     // one lbuf slice
#define OSLICE ((size_t)NBH * SEQ_T * DHEAD)   // one pbuf slice
#define QSC    (0.125f * 1.44269504f)   // qk-scale * log2(e), folded into Q

typedef __attribute__((ext_vector_type(8))) short short8;   // 8 x bf16 (4 VGPRs)
typedef __attribute__((ext_vector_type(4))) float f32x4;

// round-to-nearest-even f32 -> bf16 (finite inputs only)
__device__ __forceinline__ unsigned short f2bf(float f) {
  unsigned int u = __float_as_uint(f);
  u += 0x7FFFu + ((u >> 16) & 1u);
  return (unsigned short)(u >> 16);
}
__device__ __forceinline__ float bf2f(unsigned short u) {
  return __uint_as_float((unsigned int)u << 16);
}

__device__ __forceinline__ void load_lds16(const unsigned short* g, unsigned short* l) {
  __builtin_amdgcn_global_load_lds((const __attribute__((address_space(1))) void*)g,
                                   (__attribute__((address_space(3))) void*)l, 16, 0, 0);
}

// ---------------------------------------------------------------------------
// Prep (fused): [0,2048): x fp32->bf16. [2048,2184): Wt transpose.
// [2184,2192): zero Wt pad rows 1088..1151. [2192,2200): W_out -> Wob[n][k]
// bf16 transpose (for out_merge MFMA).
// ---------------------------------------------------------------------------
__global__ __launch_bounds__(256) void prep(const float* __restrict__ x,
                                            const float* __restrict__ W,
                                            const float* __restrict__ Wout,
                                            unsigned short* __restrict__ xb,
                                            unsigned short* __restrict__ Wt,
                                            unsigned short* __restrict__ Wob) {
  const int bx = blockIdx.x;
  const int tid = threadIdx.x;
  if (bx < 2048) {
    const size_t i0 = ((size_t)bx * 256 + tid) * 8;
    float4 a = *(const float4*)(x + i0);
    float4 b = *(const float4*)(x + i0 + 4);
    ushort4 u0, u1;
    u0.x = f2bf(a.x); u0.y = f2bf(a.y); u0.z = f2bf(a.z); u0.w = f2bf(a.w);
    u1.x = f2bf(b.x); u1.y = f2bf(b.y); u1.z = f2bf(b.z); u1.w = f2bf(b.w);
    *(ushort4*)(xb + i0) = u0;
    *(ushort4*)(xb + i0 + 4) = u1;
    return;
  }
  if (bx >= 2184 && bx < 2192) {   // zero-fill Wt rows [1088,1152)
    const int z = bx - 2184;          // 0..7
    const size_t base = (size_t)NQKV * HIDDEN + ((size_t)z * 256 + tid) * 16;
    uint4 zero = {0u, 0u, 0u, 0u};
    *(uint4*)(Wt + base) = zero;
    *(uint4*)(Wt + base + 8) = zero;
    return;
  }
  if (bx >= 2192) {   // Wob[n][k] = bf16(W_out[k][n]), 8 blocks of 64 n-cols
    const int n0 = (bx - 2192) * 64;
    __shared__ float T[64 * 65];
#pragma unroll
    for (int i = 0; i < 4; ++i) {
      int f = tid + i * 256;
      int r = f >> 4;            // k row 0..63
      int c4 = (f & 15) * 4;     // n col within tile
      float4 v = *(const float4*)(Wout + (size_t)r * HIDDEN + n0 + c4);
      T[r * 65 + c4 + 0] = v.x;
      T[r * 65 + c4 + 1] = v.y;
      T[r * 65 + c4 + 2] = v.z;
      T[r * 65 + c4 + 3] = v.w;
    }
    __syncthreads();
#pragma unroll
    for (int i = 0; i < 4; ++i) {
      int f = tid + i * 256;
      int n = f >> 4;
      int k4 = (f & 15) * 4;
      ushort4 u;
      u.x = f2bf(T[(k4 + 0) * 65 + n]);
      u.y = f2bf(T[(k4 + 1) * 65 + n]);
      u.z = f2bf(T[(k4 + 2) * 65 + n]);
      u.w = f2bf(T[(k4 + 3) * 65 + n]);
      *(ushort4*)(Wob + (size_t)(n0 + n) * DHEAD + k4) = u;
    }
    return;
  }
  // Wt[n][k] = bf16(W[k][n]) via 64x64 LDS transpose
  const int idx = bx - 2048;          // 0..135
  const int n0 = (idx % 17) * 64;
  const int k0 = (idx / 17) * 64;
  __shared__ float T[64 * 65];
#pragma unroll
  for (int i = 0; i < 4; ++i) {
    int f = tid + i * 256;
    int r = f >> 4;
    int c4 = (f & 15) * 4;
    float4 v = *(const float4*)(W + (size_t)(k0 + r) * NQKV + n0 + c4);
    T[r * 65 + c4 + 0] = v.x;
    T[r * 65 + c4 + 1] = v.y;
    T[r * 65 + c4 + 2] = v.z;
    T[r * 65 + c4 + 3] = v.w;
  }
  __syncthreads();
#pragma unroll
  for (int i = 0; i < 4; ++i) {
    int f = tid + i * 256;
    int n = f >> 4;
    int k4 = (f & 15) * 4;
    ushort4 u;
    u.x = f2bf(T[(k4 + 0) * 65 + n]);
    u.y = f2bf(T[(k4 + 1) * 65 + n]);
    u.z = f2bf(T[(k4 + 2) * 65 + n]);
    u.w = f2bf(T[(k4 + 3) * 65 + n]);
    *(ushort4*)(Wt + (size_t)(n0 + n) * HIDDEN + k0 + k4) = u;
  }
}

// ---------------------------------------------------------------------------
// Kernel 1: qkv = xb @ Wt^T via bf16 MFMA.  BM=128, BN=128 (N padded 1152),
// BK=64.  XCD-aware 1D swizzle.  Q columns (bn<4) pre-scaled by QSC.
// bn==8 blocks hold V in accumulators -> fused V-transpose epilogue writes
// vt[b][d][k0+n] = V[b][k0+sigma(n)][d] directly.
// sigma(n) = 32*n5 + 16*n2 + 4*(n4n3) + (n1n0).
// ---------------------------------------------------------------------------
__global__ __launch_bounds__(256, 3) void qkv_mfma(const unsigned short* __restrict__ Xb,
                                                   const unsigned short* __restrict__ Wt,
                                                   unsigned short* __restrict__ Y,
                                                   unsigned short* __restrict__ vt) {
  __shared__ __align__(16) unsigned short SH[2 * 128 * 64];   // As | Bs (and V-stage alias)
  unsigned short* As = SH;
  unsigned short* Bs = SH + 128 * 64;
  const int L = blockIdx.x;       // 0..575
  const int slot = L >> 3;        // 0..71
  const int bm = (L & 7) * 8 + (slot & 7);   // 0..63
  const int bn = slot >> 3;                  // 0..8
  const int tid = threadIdx.x;
  const int wave = tid >> 6;
  const int lane = tid & 63;
  const int quad = lane >> 4;
  const int l15 = lane & 15;
  const int lrow = lane >> 3;
  const int lchunk = lane & 7;

  const unsigned short* xrow = Xb + (size_t)bm * 128 * HIDDEN;
  const unsigned short* wrow = Wt + (size_t)bn * 128 * HIDDEN;

  f32x4 acc[2][8];
#pragma unroll
  for (int mt = 0; mt < 2; ++mt)
#pragma unroll
    for (int nt = 0; nt < 8; ++nt) acc[mt][nt] = (f32x4){0.f, 0.f, 0.f, 0.f};

  for (int k0 = 0; k0 < HIDDEN; k0 += 64) {
    __syncthreads();
#pragma unroll
    for (int c = 0; c < 4; ++c) {
      int call = wave * 4 + c;
      int m = call * 8 + lrow;
      int clog = lchunk ^ lrow;
      load_lds16(xrow + (size_t)m * HIDDEN + k0 + clog * 8, &As[call * 512]);
      load_lds16(wrow + (size_t)m * HIDDEN + k0 + clog * 8, &Bs[call * 512]);
    }
    __syncthreads();

#pragma unroll
    for (int ks = 0; ks < 2; ++ks) {
      short8 a[2], b[8];
#pragma unroll
      for (int mt = 0; mt < 2; ++mt) {
        int m = wave * 32 + mt * 16 + l15;
        int phys = (ks * 4 + quad) ^ (l15 & 7);
        a[mt] = *(const short8*)&As[m * 64 + phys * 8];
      }
#pragma unroll
      for (int nt = 0; nt < 8; ++nt) {
        int n = nt * 16 + l15;
        int phys = (ks * 4 + quad) ^ (l15 & 7);
        b[nt] = *(const short8*)&Bs[n * 64 + phys * 8];
      }
#pragma unroll
      for (int mt = 0; mt < 2; ++mt)
#pragma unroll
        for (int nt = 0; nt < 8; ++nt)
          acc[mt][nt] = __builtin_amdgcn_mfma_f32_16x16x32_bf16(a[mt], b[nt], acc[mt][nt], 0, 0, 0);
    }
  }

  if (bn != 8) {
    const float qs = (bn < 4) ? QSC : 1.0f;   // pre-scale Q region (cols < 512)
#pragma unroll
    for (int mt = 0; mt < 2; ++mt)
#pragma unroll
      for (int r = 0; r < 4; ++r) {
        int row = bm * 128 + wave * 32 + mt * 16 + quad * 4 + r;
#pragma unroll
        for (int nt = 0; nt < 8; ++nt) {
          int col = bn * 128 + nt * 16 + l15;
          Y[(size_t)row * QPITCH + col] = f2bf(acc[mt][nt][r] * qs);
        }
      }
  } else {
    // ---- fused V-transpose: acc[mt][nt<4] = V[bm*128 + lr][d = nt*16+l15]
    __syncthreads();                       // all waves done reading As/Bs
    unsigned short* Vs = SH;               // [64 d][pitch 130] bf16 (16.6 KB)
#pragma unroll
    for (int mt = 0; mt < 2; ++mt)
#pragma unroll
      for (int nt = 0; nt < 4; ++nt)
#pragma unroll
        for (int r = 0; r < 4; ++r) {
          int lr = wave * 32 + mt * 16 + quad * 4 + r;
          int d = nt * 16 + l15;
          Vs[d * 130 + lr] = f2bf(acc[mt][nt][r]);
        }
    __syncthreads();
    const int bb = bm >> 4;                // batch
    const int t0 = (bm & 15) * 128;        // base t within batch
    const int half = lane >> 5;            // which 64-block of the 128 rows
    const int np = lane & 31;              // n-pair index (n = 2*np, 2*np+1)
    // sigma(2*np): bit0 of n is 0; sigma passes bit0 through -> pair stays adjacent
    const int s2 = ((np & 16) << 1) | ((np & 2) << 3) | (np & 12) | ((np & 1) << 1);
#pragma unroll
    for (int i = 0; i < 16; ++i) {
      int d = i * 4 + wave;
      unsigned int v = *(const unsigned int*)&Vs[d * 130 + half * 64 + s2];
      *(unsigned int*)&vt[((size_t)bb * DHEAD + d) * SEQ_T + t0 + half * 64 + 2 * np] = v;
    }
  }
}

// ---------------------------------------------------------------------------
// Kernel 2: flash attention pass, QBLK=256 (4 strips of 64 q-rows), balanced
// adaptive k-split: q-tile qt (256 rows) gets ns = qt/2+1 split blocks, each
// handling 4..8 k-tiles -> near-uniform work per block.  Decode from
// blockIdx.y is closed-form scalar (no tables).  Each staged K/V tile now
// feeds 256 q-rows (2x the old 128): LDS-read cost and K/V re-fetch traffic
// per unit work are HALVED; barriers per unit work halved.
// Swapped-operand QK^T keeps P lane-local; P packed to bf16 A-frags in
// registers (vt's sigma order absorbs the kpos permutation).  l via MFMA vs
// all-ones.  (256,2): ~200 VGPR budget, 2 blocks/CU (64 KB LDS).
// ---------------------------------------------------------------------------
__global__ __launch_bounds__(256, 2) void attn_pass(const unsigned short* __restrict__ qkv,
                                                    const unsigned short* __restrict__ vt,
                                                    unsigned short* __restrict__ pbuf,
                                                    float* __restrict__ lbuf) {
  const int bh = blockIdx.x;       // 0..31
  const int yy = 19 - blockIdx.y;  // big qt dispatched first
  // qt = #thresholds {1,2,4,6,9,12,16} <= yy ;  C(qt) = m(m+1) or (m+1)^2
  const int qt = (yy >= 1) + (yy >= 2) + (yy >= 4) + (yy >= 6) +
                 (yy >= 9) + (yy >= 12) + (yy >= 16);
  const int m = qt >> 1;
  const int Cq = (qt & 1) ? (m + 1) * (m + 1) : m * (m + 1);
  const int si = yy - Cq;                 // split index 0..ns-1
  const int ns = m + 1;                   // splits for this qt
  const int ntile = 4 * qt + 4;           // causal k-tiles for this q-tile
  const int kbeg = (si * ntile) / ns;
  const int kend = ((si + 1) * ntile) / ns - 1;   // inclusive

  const int b = bh >> 3;
  const int h = bh & 7;
  const int tid = threadIdx.x;
  const int wave = tid >> 6;
  const int lane = tid & 63;
  const int quad = lane >> 4;
  const int l15 = lane & 15;

  __shared__ __align__(16) unsigned short Ks[2][64 * 64];   // XOR-swizzled chunks
  __shared__ __align__(16) unsigned short Vts[2][64 * 64];  // XOR-swizzled chunks

  const unsigned short* bq = qkv + (size_t)b * SEQ_T * QPITCH;
  const unsigned short* bvt = vt + (size_t)b * DHEAD * SEQ_T;

  const int q0 = qt * 256;

  // Q frags for 4 strips (pre-scaled by QSC in qkv_mfma); used as B operand
  short8 aq[4][2];
#pragma unroll
  for (int s = 0; s < 4; ++s) {
    const unsigned short* qp = bq + (size_t)(q0 + s * 64 + wave * 16 + l15) * QPITCH + h * 64 + quad * 8;
    aq[s][0] = *(const short8*)qp;
    aq[s][1] = *(const short8*)(qp + 32);
  }

  f32x4 o[4][4];
#pragma unroll
  for (int s = 0; s < 4; ++s)
#pragma unroll
    for (int t = 0; t < 4; ++t) o[s][t] = (f32x4){0.f, 0.f, 0.f, 0.f};
  f32x4 ol[4];
#pragma unroll
  for (int s = 0; s < 4; ++s) ol[s] = (f32x4){0.f, 0.f, 0.f, 0.f};
  const short8 vone = {(short)0x3F80, (short)0x3F80, (short)0x3F80, (short)0x3F80,
                       (short)0x3F80, (short)0x3F80, (short)0x3F80, (short)0x3F80};

  const int srow = tid >> 3;               // 0..31 staging row-within-call
  const int sch = (tid & 7) ^ (srow & 7);  // logical chunk to fetch
  const int ph0 = (quad ^ (l15 & 7)) * 8;  // frag-read physical chunk offset

  // prologue: stage first tile into buffer 0
#pragma unroll
  for (int c = 0; c < 2; ++c) {
    load_lds16(bq + (size_t)(kbeg * 64 + c * 32 + srow) * QPITCH + 512 + h * 64 + sch * 8,
               &Ks[0][c * 2048 + wave * 512]);
    load_lds16(bvt + (size_t)(c * 32 + srow) * SEQ_T + kbeg * 64 + sch * 8,
               &Vts[0][c * 2048 + wave * 512]);
  }

  for (int kt = kbeg; kt <= kend; ++kt) {
    const int k0 = kt * 64;
    const int cur = (kt - kbeg) & 1;
    __syncthreads();   // drains loads issued one full iteration ago
    if (kt < kend) {   // stage next tile into the other buffer (post-barrier)
      const int kn = (kt + 1) * 64;
      const int nxt = cur ^ 1;
#pragma unroll
      for (int c = 0; c < 2; ++c) {
        load_lds16(bq + (size_t)(kn + c * 32 + srow) * QPITCH + 512 + h * 64 + sch * 8,
                   &Ks[nxt][c * 2048 + wave * 512]);
        load_lds16(bvt + (size_t)(c * 32 + srow) * SEQ_T + kn + sch * 8,
                   &Vts[nxt][c * 2048 + wave * 512]);
      }
    }

    const unsigned short* ksb = Ks[cur];
    const unsigned short* vsb = Vts[cur];

    // ---- K and V^T frags ONCE per tile (shared by all 4 strips)
    short8 bk[4][2], bv[4][2];
#pragma unroll
    for (int t = 0; t < 4; ++t) {
      const unsigned short* kp = &ksb[(l15 + 16 * t) * 64];
      bk[t][0] = *(const short8*)(kp + ph0);
      bk[t][1] = *(const short8*)(kp + (ph0 ^ 32));
      const unsigned short* vp = &vsb[(l15 + 16 * t) * 64];
      bv[t][0] = *(const short8*)(vp + ph0);
      bv[t][1] = *(const short8*)(vp + (ph0 ^ 32));
    }

    // ---- per strip: S^T = K Q^T -> exp2 -> in-register bf16 A-frag pack -> PV
#pragma unroll
    for (int s = 0; s < 4; ++s) {
      f32x4 pr[4];
#pragma unroll
      for (int t = 0; t < 4; ++t) {
        f32x4 sv = (f32x4){0.f, 0.f, 0.f, 0.f};
        sv = __builtin_amdgcn_mfma_f32_16x16x32_bf16(bk[t][0], aq[s][0], sv, 0, 0, 0);
        sv = __builtin_amdgcn_mfma_f32_16x16x32_bf16(bk[t][1], aq[s][1], sv, 0, 0, 0);
        pr[t] = sv;   // S^T: col l15 = q-row, row quad*4+r = kpos (in 16t block)
      }
      const int qrow = q0 + s * 64 + wave * 16 + l15;
      const bool needMask = (k0 + 63) > (q0 + s * 64);
#pragma unroll
      for (int t = 0; t < 4; ++t)
#pragma unroll
        for (int r = 0; r < 4; ++r) {
          float p = __builtin_amdgcn_exp2f(pr[t][r]);
          if (needMask)
            p = (k0 + 16 * t + 4 * quad + r <= qrow) ? p : 0.f;
          pr[t][r] = p;
        }
      // pack: A-frag half c, element j  <-  pr[2c + (j>>2)][j&3]
      short8 ap[2];
#pragma unroll
      for (int c = 0; c < 2; ++c) {
        union { unsigned int u[4]; short8 v; } pk;
        pk.u[0] = __builtin_amdgcn_perm(__float_as_uint(pr[2 * c][1]),
                                        __float_as_uint(pr[2 * c][0]), 0x07060302u);
        pk.u[1] = __builtin_amdgcn_perm(__float_as_uint(pr[2 * c][3]),
                                        __float_as_uint(pr[2 * c][2]), 0x07060302u);
        pk.u[2] = __builtin_amdgcn_perm(__float_as_uint(pr[2 * c + 1][1]),
                                        __float_as_uint(pr[2 * c + 1][0]), 0x07060302u);
        pk.u[3] = __builtin_amdgcn_perm(__float_as_uint(pr[2 * c + 1][3]),
                                        __float_as_uint(pr[2 * c + 1][2]), 0x07060302u);
        ap[c] = pk.v;
      }
      // l via MFMA against ones: C row quad*4+r holds sum_k P (dup over cols)
      ol[s] = __builtin_amdgcn_mfma_f32_16x16x32_bf16(ap[0], vone, ol[s], 0, 0, 0);
      ol[s] = __builtin_amdgcn_mfma_f32_16x16x32_bf16(ap[1], vone, ol[s], 0, 0, 0);
      // O += P V
#pragma unroll
      for (int t = 0; t < 4; ++t) {
        o[s][t] = __builtin_amdgcn_mfma_f32_16x16x32_bf16(ap[0], bv[t][0], o[s][t], 0, 0, 0);
        o[s][t] = __builtin_amdgcn_mfma_f32_16x16x32_bf16(ap[1], bv[t][1], o[s][t], 0, 0, 0);
      }
    }
  }

  // ---- epilogue: bf16 partial O + per-row l into slice si
  unsigned short* pb = pbuf + (size_t)si * OSLICE;
#pragma unroll
  for (int s = 0; s < 4; ++s) {
#pragma unroll
    for (int r = 0; r < 4; ++r) {
      const int trow = q0 + s * 64 + wave * 16 + quad * 4 + r;
      if (l15 == 0) lbuf[si * LPITCH + bh * SEQ_T + trow] = ol[s][r];
      const size_t base = ((size_t)bh * SEQ_T + trow) * DHEAD;
#pragma unroll
      for (int t = 0; t < 4; ++t) pb[base + l15 + 16 * t] = f2bf(o[s][t][r]);
    }
  }
}

// ---------------------------------------------------------------------------
// Kernel 3 (fused): attn_vec = (Sum_si O_si)/(Sum_si l_si); out =
// mean_h(attn_vec) @ W_out via MFMA vs Wob.  ns per row = (t>>9)+1
// (wave-uniform within a 16-row block).
// ---------------------------------------------------------------------------
__global__ __launch_bounds__(256) void out_merge(const unsigned short* __restrict__ pbuf,
                                                 const float* __restrict__ lbuf,
                                                 const unsigned short* __restrict__ Wob,
                                                 float* __restrict__ attnv,
                                                 float* __restrict__ out) {
  const int row0 = blockIdx.x * 16;   // global row = b*2048 + t
  const int tid = threadIdx.x;
  __shared__ float Ms[16][66];        // pitch 66: conflict-free frag reads

  {
    const int lr = tid >> 4;
    const int d0 = (tid & 15) * 4;
    const int row = row0 + lr;
    const int b = row >> 11;
    const int t = row & 2047;
    const int ns = (t >> 9) + 1;      // qt/2 + 1, qt = t>>8
    float s0 = 0.f, s1 = 0.f, s2 = 0.f, s3 = 0.f;
#pragma unroll
    for (int hh = 0; hh < NHEAD; ++hh) {
      const size_t ridx = (size_t)(b * NHEAD + hh) * SEQ_T + t;
      float l = 0.f;
      float4 macc = {0.f, 0.f, 0.f, 0.f};
      const size_t idx = ridx * DHEAD + d0;
#pragma unroll
      for (int si = 0; si < 4; ++si) {
        if (si < ns) {
          l += lbuf[si * LPITCH + ridx];
          ushort4 A = *(const ushort4*)(pbuf + si * OSLICE + idx);
          macc.x += bf2f(A.x);
          macc.y += bf2f(A.y);
          macc.z += bf2f(A.z);
          macc.w += bf2f(A.w);
        }
      }
      const float inv = 1.0f / l;
      float4 mv;
      mv.x = macc.x * inv;
      mv.y = macc.y * inv;
      mv.z = macc.z * inv;
      mv.w = macc.w * inv;
      *(float4*)(attnv + idx) = mv;
      s0 += mv.x; s1 += mv.y; s2 += mv.z; s3 += mv.w;
    }
    Ms[lr][d0 + 0] = s0 * 0.125f;
    Ms[lr][d0 + 1] = s1 * 0.125f;
    Ms[lr][d0 + 2] = s2 * 0.125f;
    Ms[lr][d0 + 3] = s3 * 0.125f;
  }
  __syncthreads();

  // ---- out[16 rows][512] = Ms @ W_out via MFMA; wave w owns cols w*128..+128
  const int wv = tid >> 6;
  const int lane = tid & 63;
  const int quad = lane >> 4;
  const int l15 = lane & 15;

  short8 am[2];
  {
    union { unsigned short us[16]; short8 v[2]; } u;
#pragma unroll
    for (int j = 0; j < 8; ++j) {
      u.us[j] = f2bf(Ms[l15][quad * 8 + j]);
      u.us[8 + j] = f2bf(Ms[l15][32 + quad * 8 + j]);
    }
    am[0] = u.v[0];
    am[1] = u.v[1];
  }

#pragma unroll
  for (int nt = 0; nt < 8; ++nt) {
    const int n = wv * 128 + nt * 16 + l15;
    short8 b0 = *(const short8*)&Wob[(size_t)n * DHEAD + quad * 8];
    short8 b1 = *(const short8*)&Wob[(size_t)n * DHEAD + 32 + quad * 8];
    f32x4 c = (f32x4){0.f, 0.f, 0.f, 0.f};
    c = __builtin_amdgcn_mfma_f32_16x16x32_bf16(am[0], b0, c, 0, 0, 0);
    c = __builtin_amdgcn_mfma_f32_16x16x32_bf16(am[1], b1, c, 0, 0, 0);
#pragma unroll
    for (int r = 0; r < 4; ++r)
      out[(size_t)(row0 + quad * 4 + r) * HIDDEN + n] = c[r];
  }
}

// ---------------------------------------------------------------------------
extern "C" void kernel_launch(void* const* d_in, const int* in_sizes, int n_in,
                              void* d_out, int out_size, void* d_ws, size_t ws_size,
                              hipStream_t stream) {
  const float* x     = (const float*)d_in[0];   // (4,2048,512)
  const float* W_qkv = (const float*)d_in[1];   // (512,1088)
  const float* W_out = (const float*)d_in[2];   // (64,512)

  float* out      = (float*)d_out;                              // (4,2048,512)
  float* attn_vec = out + (size_t)BATCH * SEQ_T * HIDDEN;       // (4,8,2048,64)

  unsigned short* qkv  = (unsigned short*)d_ws;                 // 8192x1152 bf16 = 18.9 MB
  unsigned short* vt   = qkv + (size_t)NROWS * QPITCH;          // 1.0 MB bf16
  unsigned short* xb   = vt + (size_t)BATCH * DHEAD * SEQ_T;    // 8.4 MB bf16
  unsigned short* Wt   = xb + (size_t)NROWS * HIDDEN;           // 1152x512 bf16 = 1.2 MB
  unsigned short* pbuf = Wt + (size_t)QPITCH * HIDDEN;          // 4 x 8.4 MB bf16 partial O
  float*          lbuf = (float*)(pbuf + 4 * OSLICE);           // 4 x 0.26 MB
  unsigned short* Wob  = (unsigned short*)(lbuf + 4 * LPITCH);  // 512x64 bf16 = 64 KB

  prep<<<dim3(2048 + 136 + 8 + 8), 256, 0, stream>>>(x, W_qkv, W_out, xb, Wt, Wob);
  qkv_mfma<<<dim3(576), 256, 0, stream>>>(xb, Wt, qkv, vt);
  attn_pass<<<dim3(NBH, 20), 256, 0, stream>>>(qkv, vt, pbuf, lbuf);
  out_merge<<<dim3(512), 256, 0, stream>>>(pbuf, lbuf, Wob, attn_vec, out);
}

// Round 4
// 135.439 us; speedup vs baseline: 1.0944x; 1.0944x over previous
//
#include <hip/hip_runtime.h>
#include <hip/hip_bf16.h>

// Problem constants (reference: InterpretableMultiHeadAttention)
#define NHEAD  8
#define DHEAD  64
#define HIDDEN 512
#define SEQ_T  2048
#define BATCH  4
#define NQKV   1088          // (2*8+1)*64 true width
#define QPITCH 1152          // padded to 9*128 for BN=128 GEMM tiles
#define NT     32            // 2048/64 k-tiles
#define NROWS  (BATCH * SEQ_T)   // 8192
#define NBH    (BATCH * NHEAD)   // 32
#define LPITCH (NBH * SEQ_T)     // one lbuf slice
#define OSLICE ((size_t)NBH * SEQ_T * DHEAD)   // one pbuf slice
#define QSC    (0.125f * 1.44269504f)   // qk-scale * log2(e), folded into Q

typedef __attribute__((ext_vector_type(8))) short short8;   // 8 x bf16 (4 VGPRs)
typedef __attribute__((ext_vector_type(4))) float f32x4;

// round-to-nearest-even f32 -> bf16 (finite inputs only)
__device__ __forceinline__ unsigned short f2bf(float f) {
  unsigned int u = __float_as_uint(f);
  u += 0x7FFFu + ((u >> 16) & 1u);
  return (unsigned short)(u >> 16);
}
__device__ __forceinline__ float bf2f(unsigned short u) {
  return __uint_as_float((unsigned int)u << 16);
}

__device__ __forceinline__ void load_lds16(const unsigned short* g, unsigned short* l) {
  __builtin_amdgcn_global_load_lds((const __attribute__((address_space(1))) void*)g,
                                   (__attribute__((address_space(3))) void*)l, 16, 0, 0);
}

// ---------------------------------------------------------------------------
// Prep (fused): [0,2048): x fp32->bf16. [2048,2184): Wt transpose.
// [2184,2192): zero Wt pad rows 1088..1151. [2192,2200): W_out -> Wob[n][k]
// bf16 transpose (for out_merge MFMA).
// ---------------------------------------------------------------------------
__global__ __launch_bounds__(256) void prep(const float* __restrict__ x,
                                            const float* __restrict__ W,
                                            const float* __restrict__ Wout,
                                            unsigned short* __restrict__ xb,
                                            unsigned short* __restrict__ Wt,
                                            unsigned short* __restrict__ Wob) {
  const int bx = blockIdx.x;
  const int tid = threadIdx.x;
  if (bx < 2048) {
    const size_t i0 = ((size_t)bx * 256 + tid) * 8;
    float4 a = *(const float4*)(x + i0);
    float4 b = *(const float4*)(x + i0 + 4);
    ushort4 u0, u1;
    u0.x = f2bf(a.x); u0.y = f2bf(a.y); u0.z = f2bf(a.z); u0.w = f2bf(a.w);
    u1.x = f2bf(b.x); u1.y = f2bf(b.y); u1.z = f2bf(b.z); u1.w = f2bf(b.w);
    *(ushort4*)(xb + i0) = u0;
    *(ushort4*)(xb + i0 + 4) = u1;
    return;
  }
  if (bx >= 2184 && bx < 2192) {   // zero-fill Wt rows [1088,1152)
    const int z = bx - 2184;          // 0..7
    const size_t base = (size_t)NQKV * HIDDEN + ((size_t)z * 256 + tid) * 16;
    uint4 zero = {0u, 0u, 0u, 0u};
    *(uint4*)(Wt + base) = zero;
    *(uint4*)(Wt + base + 8) = zero;
    return;
  }
  if (bx >= 2192) {   // Wob[n][k] = bf16(W_out[k][n]), 8 blocks of 64 n-cols
    const int n0 = (bx - 2192) * 64;
    __shared__ float T[64 * 65];
#pragma unroll
    for (int i = 0; i < 4; ++i) {
      int f = tid + i * 256;
      int r = f >> 4;            // k row 0..63
      int c4 = (f & 15) * 4;     // n col within tile
      float4 v = *(const float4*)(Wout + (size_t)r * HIDDEN + n0 + c4);
      T[r * 65 + c4 + 0] = v.x;
      T[r * 65 + c4 + 1] = v.y;
      T[r * 65 + c4 + 2] = v.z;
      T[r * 65 + c4 + 3] = v.w;
    }
    __syncthreads();
#pragma unroll
    for (int i = 0; i < 4; ++i) {
      int f = tid + i * 256;
      int n = f >> 4;
      int k4 = (f & 15) * 4;
      ushort4 u;
      u.x = f2bf(T[(k4 + 0) * 65 + n]);
      u.y = f2bf(T[(k4 + 1) * 65 + n]);
      u.z = f2bf(T[(k4 + 2) * 65 + n]);
      u.w = f2bf(T[(k4 + 3) * 65 + n]);
      *(ushort4*)(Wob + (size_t)(n0 + n) * DHEAD + k4) = u;
    }
    return;
  }
  // Wt[n][k] = bf16(W[k][n]) via 64x64 LDS transpose
  const int idx = bx - 2048;          // 0..135
  const int n0 = (idx % 17) * 64;
  const int k0 = (idx / 17) * 64;
  __shared__ float T[64 * 65];
#pragma unroll
  for (int i = 0; i < 4; ++i) {
    int f = tid + i * 256;
    int r = f >> 4;
    int c4 = (f & 15) * 4;
    float4 v = *(const float4*)(W + (size_t)(k0 + r) * NQKV + n0 + c4);
    T[r * 65 + c4 + 0] = v.x;
    T[r * 65 + c4 + 1] = v.y;
    T[r * 65 + c4 + 2] = v.z;
    T[r * 65 + c4 + 3] = v.w;
  }
  __syncthreads();
#pragma unroll
  for (int i = 0; i < 4; ++i) {
    int f = tid + i * 256;
    int n = f >> 4;
    int k4 = (f & 15) * 4;
    ushort4 u;
    u.x = f2bf(T[(k4 + 0) * 65 + n]);
    u.y = f2bf(T[(k4 + 1) * 65 + n]);
    u.z = f2bf(T[(k4 + 2) * 65 + n]);
    u.w = f2bf(T[(k4 + 3) * 65 + n]);
    *(ushort4*)(Wt + (size_t)(n0 + n) * HIDDEN + k0 + k4) = u;
  }
}

// ---------------------------------------------------------------------------
// Kernel 1: qkv = xb @ Wt^T via bf16 MFMA.  BM=128, BN=128 (N padded 1152),
// BK=64.  XCD-aware 1D swizzle.  Q columns (bn<4) pre-scaled by QSC.
// bn==8 blocks compute ONLY nt<4 (cols 1024..1088 = V; pad cols skipped) and
// stage only 64 Wt rows -> ~half the MFMA/staging in that path.  V epilogue
// writes vt[b][d][k0+n] = V[b][k0+sigma(n)][d] directly.
// sigma(n) = 32*n5 + 16*n2 + 4*(n4n3) + (n1n0).
// ---------------------------------------------------------------------------
__global__ __launch_bounds__(256, 3) void qkv_mfma(const unsigned short* __restrict__ Xb,
                                                   const unsigned short* __restrict__ Wt,
                                                   unsigned short* __restrict__ Y,
                                                   unsigned short* __restrict__ vt) {
  __shared__ __align__(16) unsigned short SH[2 * 128 * 64];   // As | Bs (and V-stage alias)
  unsigned short* As = SH;
  unsigned short* Bs = SH + 128 * 64;
  const int L = blockIdx.x;       // 0..575
  const int slot = L >> 3;        // 0..71
  const int bm = (L & 7) * 8 + (slot & 7);   // 0..63
  const int bn = slot >> 3;                  // 0..8
  const int tid = threadIdx.x;
  const int wave = tid >> 6;
  const int lane = tid & 63;
  const int quad = lane >> 4;
  const int l15 = lane & 15;
  const int lrow = lane >> 3;
  const int lchunk = lane & 7;

  const unsigned short* xrow = Xb + (size_t)bm * 128 * HIDDEN;
  const unsigned short* wrow = Wt + (size_t)bn * 128 * HIDDEN;

  if (bn != 8) {
    f32x4 acc[2][8];
#pragma unroll
    for (int mt = 0; mt < 2; ++mt)
#pragma unroll
      for (int nt = 0; nt < 8; ++nt) acc[mt][nt] = (f32x4){0.f, 0.f, 0.f, 0.f};

    for (int k0 = 0; k0 < HIDDEN; k0 += 64) {
      __syncthreads();
#pragma unroll
      for (int c = 0; c < 4; ++c) {
        int call = wave * 4 + c;
        int m = call * 8 + lrow;
        int clog = lchunk ^ lrow;
        load_lds16(xrow + (size_t)m * HIDDEN + k0 + clog * 8, &As[call * 512]);
        load_lds16(wrow + (size_t)m * HIDDEN + k0 + clog * 8, &Bs[call * 512]);
      }
      __syncthreads();

#pragma unroll
      for (int ks = 0; ks < 2; ++ks) {
        short8 a[2], b[8];
#pragma unroll
        for (int mt = 0; mt < 2; ++mt) {
          int m = wave * 32 + mt * 16 + l15;
          int phys = (ks * 4 + quad) ^ (l15 & 7);
          a[mt] = *(const short8*)&As[m * 64 + phys * 8];
        }
#pragma unroll
        for (int nt = 0; nt < 8; ++nt) {
          int n = nt * 16 + l15;
          int phys = (ks * 4 + quad) ^ (l15 & 7);
          b[nt] = *(const short8*)&Bs[n * 64 + phys * 8];
        }
#pragma unroll
        for (int mt = 0; mt < 2; ++mt)
#pragma unroll
          for (int nt = 0; nt < 8; ++nt)
            acc[mt][nt] = __builtin_amdgcn_mfma_f32_16x16x32_bf16(a[mt], b[nt], acc[mt][nt], 0, 0, 0);
      }
    }

    const float qs = (bn < 4) ? QSC : 1.0f;   // pre-scale Q region (cols < 512)
#pragma unroll
    for (int mt = 0; mt < 2; ++mt)
#pragma unroll
      for (int r = 0; r < 4; ++r) {
        int row = bm * 128 + wave * 32 + mt * 16 + quad * 4 + r;
#pragma unroll
        for (int nt = 0; nt < 8; ++nt) {
          int col = bn * 128 + nt * 16 + l15;
          Y[(size_t)row * QPITCH + col] = f2bf(acc[mt][nt][r] * qs);
        }
      }
  } else {
    // ---- V-only path: 64 out-cols (nt<4), half B staging
    f32x4 acc[2][4];
#pragma unroll
    for (int mt = 0; mt < 2; ++mt)
#pragma unroll
      for (int nt = 0; nt < 4; ++nt) acc[mt][nt] = (f32x4){0.f, 0.f, 0.f, 0.f};

    for (int k0 = 0; k0 < HIDDEN; k0 += 64) {
      __syncthreads();
#pragma unroll
      for (int c = 0; c < 4; ++c) {
        int call = wave * 4 + c;
        int m = call * 8 + lrow;
        int clog = lchunk ^ lrow;
        load_lds16(xrow + (size_t)m * HIDDEN + k0 + clog * 8, &As[call * 512]);
        if (wave < 2)   // Bs rows 0..63 only
          load_lds16(wrow + (size_t)m * HIDDEN + k0 + clog * 8, &Bs[call * 512]);
      }
      __syncthreads();

#pragma unroll
      for (int ks = 0; ks < 2; ++ks) {
        short8 a[2], b[4];
#pragma unroll
        for (int mt = 0; mt < 2; ++mt) {
          int m = wave * 32 + mt * 16 + l15;
          int phys = (ks * 4 + quad) ^ (l15 & 7);
          a[mt] = *(const short8*)&As[m * 64 + phys * 8];
        }
#pragma unroll
        for (int nt = 0; nt < 4; ++nt) {
          int n = nt * 16 + l15;
          int phys = (ks * 4 + quad) ^ (l15 & 7);
          b[nt] = *(const short8*)&Bs[n * 64 + phys * 8];
        }
#pragma unroll
        for (int mt = 0; mt < 2; ++mt)
#pragma unroll
          for (int nt = 0; nt < 4; ++nt)
            acc[mt][nt] = __builtin_amdgcn_mfma_f32_16x16x32_bf16(a[mt], b[nt], acc[mt][nt], 0, 0, 0);
      }
    }

    // ---- fused V-transpose: acc[mt][nt] = V[bm*128 + lr][d = nt*16+l15]
    __syncthreads();                       // all waves done reading As/Bs
    unsigned short* Vs = SH;               // [64 d][pitch 130] bf16 (16.6 KB)
#pragma unroll
    for (int mt = 0; mt < 2; ++mt)
#pragma unroll
      for (int nt = 0; nt < 4; ++nt)
#pragma unroll
        for (int r = 0; r < 4; ++r) {
          int lr = wave * 32 + mt * 16 + quad * 4 + r;
          int d = nt * 16 + l15;
          Vs[d * 130 + lr] = f2bf(acc[mt][nt][r]);
        }
    __syncthreads();
    const int bb = bm >> 4;                // batch
    const int t0 = (bm & 15) * 128;        // base t within batch
    const int half = lane >> 5;            // which 64-block of the 128 rows
    const int np = lane & 31;              // n-pair index (n = 2*np, 2*np+1)
    // sigma(2*np): bit0 of n is 0; sigma passes bit0 through -> pair stays adjacent
    const int s2 = ((np & 16) << 1) | ((np & 2) << 3) | (np & 12) | ((np & 1) << 1);
#pragma unroll
    for (int i = 0; i < 16; ++i) {
      int d = i * 4 + wave;
      unsigned int v = *(const unsigned int*)&Vs[d * 130 + half * 64 + s2];
      *(unsigned int*)&vt[((size_t)bb * DHEAD + d) * SEQ_T + t0 + half * 64 + 2 * np] = v;
    }
  }
}

// ---------------------------------------------------------------------------
// Kernel 2: flash attention pass, QBLK=128 (R2 structure: (256,3), 12
// waves/CU), BALANCED adaptive k-split: q-tile qt has ntile = 2qt+2 causal
// k-tiles, split into ns(qt) = 1 (qt<4) / 2 (qt<12) / 3 chunks -> every
// block has <= 12 tiles (was 16) at the same 1024-block grid.  Makespan
// -25% at identical per-tile code and occupancy.
// Swapped-operand QK^T keeps P lane-local; P packed to bf16 A-frags in
// registers (vt's sigma order absorbs the kpos permutation).  l via MFMA vs
// all-ones.
// ---------------------------------------------------------------------------
__global__ __launch_bounds__(256, 3) void attn_pass(const unsigned short* __restrict__ qkv,
                                                    const unsigned short* __restrict__ vt,
                                                    unsigned short* __restrict__ pbuf,
                                                    float* __restrict__ lbuf) {
  const int bh = blockIdx.x;       // 0..31
  const int yy = 31 - blockIdx.y;  // big qt dispatched first
  int qt, si, ns;
  if (yy < 4)       { qt = yy;                 si = 0;            ns = 1; }
  else if (yy < 20) { qt = 4 + ((yy - 4) >> 1); si = (yy - 4) & 1; ns = 2; }
  else              { qt = 12 + (yy - 20) / 3;  si = (yy - 20) % 3; ns = 3; }
  const int ntile = 2 * qt + 2;
  const int kbeg = (si * ntile) / ns;
  const int kend = ((si + 1) * ntile) / ns - 1;   // inclusive

  const int b = bh >> 3;
  const int h = bh & 7;
  const int tid = threadIdx.x;
  const int wave = tid >> 6;
  const int lane = tid & 63;
  const int quad = lane >> 4;
  const int l15 = lane & 15;

  __shared__ __align__(16) unsigned short Ks[2][64 * 64];   // XOR-swizzled chunks
  __shared__ __align__(16) unsigned short Vts[2][64 * 64];  // XOR-swizzled chunks

  const unsigned short* bq = qkv + (size_t)b * SEQ_T * QPITCH;
  const unsigned short* bvt = vt + (size_t)b * DHEAD * SEQ_T;

  const int q0 = qt * 128;

  // Q frags for both strips (pre-scaled by QSC in qkv_mfma); used as B operand
  short8 aq[2][2];
#pragma unroll
  for (int s = 0; s < 2; ++s) {
    const unsigned short* qp = bq + (size_t)(q0 + s * 64 + wave * 16 + l15) * QPITCH + h * 64 + quad * 8;
    aq[s][0] = *(const short8*)qp;
    aq[s][1] = *(const short8*)(qp + 32);
  }

  f32x4 o[2][4];
#pragma unroll
  for (int s = 0; s < 2; ++s)
#pragma unroll
    for (int t = 0; t < 4; ++t) o[s][t] = (f32x4){0.f, 0.f, 0.f, 0.f};
  f32x4 ol[2] = {(f32x4){0.f, 0.f, 0.f, 0.f}, (f32x4){0.f, 0.f, 0.f, 0.f}};
  const short8 vone = {(short)0x3F80, (short)0x3F80, (short)0x3F80, (short)0x3F80,
                       (short)0x3F80, (short)0x3F80, (short)0x3F80, (short)0x3F80};

  const int srow = tid >> 3;               // 0..31 staging row-within-call
  const int sch = (tid & 7) ^ (srow & 7);  // logical chunk to fetch
  const int ph0 = (quad ^ (l15 & 7)) * 8;  // frag-read physical chunk offset

  // prologue: stage first tile into buffer 0
#pragma unroll
  for (int c = 0; c < 2; ++c) {
    load_lds16(bq + (size_t)(kbeg * 64 + c * 32 + srow) * QPITCH + 512 + h * 64 + sch * 8,
               &Ks[0][c * 2048 + wave * 512]);
    load_lds16(bvt + (size_t)(c * 32 + srow) * SEQ_T + kbeg * 64 + sch * 8,
               &Vts[0][c * 2048 + wave * 512]);
  }

  for (int kt = kbeg; kt <= kend; ++kt) {
    const int k0 = kt * 64;
    const int cur = (kt - kbeg) & 1;
    __syncthreads();   // drains loads issued one full iteration ago
    if (kt < kend) {   // stage next tile into the other buffer (post-barrier)
      const int kn = (kt + 1) * 64;
      const int nxt = cur ^ 1;
#pragma unroll
      for (int c = 0; c < 2; ++c) {
        load_lds16(bq + (size_t)(kn + c * 32 + srow) * QPITCH + 512 + h * 64 + sch * 8,
                   &Ks[nxt][c * 2048 + wave * 512]);
        load_lds16(bvt + (size_t)(c * 32 + srow) * SEQ_T + kn + sch * 8,
                   &Vts[nxt][c * 2048 + wave * 512]);
      }
    }

    const unsigned short* ksb = Ks[cur];
    const unsigned short* vsb = Vts[cur];
    const bool needMask = (k0 + 63) > q0;

    // ---- K frags once (shared by both strips); used as A operand
    short8 bk[4][2];
#pragma unroll
    for (int t = 0; t < 4; ++t) {
      const unsigned short* kp = &ksb[(l15 + 16 * t) * 64];
      bk[t][0] = *(const short8*)(kp + ph0);
      bk[t][1] = *(const short8*)(kp + (ph0 ^ 32));
    }

    // ---- per strip: S^T = K Q^T -> exp2 -> in-register bf16 A-frag pack
    short8 ap[2][2];
#pragma unroll
    for (int s = 0; s < 2; ++s) {
      f32x4 pr[4];
#pragma unroll
      for (int t = 0; t < 4; ++t) {
        f32x4 sv = (f32x4){0.f, 0.f, 0.f, 0.f};
        sv = __builtin_amdgcn_mfma_f32_16x16x32_bf16(bk[t][0], aq[s][0], sv, 0, 0, 0);
        sv = __builtin_amdgcn_mfma_f32_16x16x32_bf16(bk[t][1], aq[s][1], sv, 0, 0, 0);
        pr[t] = sv;   // S^T: col l15 = q-row, row quad*4+r = kpos (in 16t block)
      }
      const int qrow = q0 + s * 64 + wave * 16 + l15;
#pragma unroll
      for (int t = 0; t < 4; ++t)
#pragma unroll
        for (int r = 0; r < 4; ++r) {
          float p = __builtin_amdgcn_exp2f(pr[t][r]);
          if (needMask)
            p = (k0 + 16 * t + 4 * quad + r <= qrow) ? p : 0.f;
          pr[t][r] = p;
        }
      // pack: A-frag half c, element j  <-  pr[2c + (j>>2)][j&3]
#pragma unroll
      for (int c = 0; c < 2; ++c) {
        union { unsigned int u[4]; short8 v; } pk;
        pk.u[0] = __builtin_amdgcn_perm(__float_as_uint(pr[2 * c][1]),
                                        __float_as_uint(pr[2 * c][0]), 0x07060302u);
        pk.u[1] = __builtin_amdgcn_perm(__float_as_uint(pr[2 * c][3]),
                                        __float_as_uint(pr[2 * c][2]), 0x07060302u);
        pk.u[2] = __builtin_amdgcn_perm(__float_as_uint(pr[2 * c + 1][1]),
                                        __float_as_uint(pr[2 * c + 1][0]), 0x07060302u);
        pk.u[3] = __builtin_amdgcn_perm(__float_as_uint(pr[2 * c + 1][3]),
                                        __float_as_uint(pr[2 * c + 1][2]), 0x07060302u);
        ap[s][c] = pk.v;
      }
      // l via MFMA against ones: C row quad*4+r holds sum_k P (dup over cols)
      ol[s] = __builtin_amdgcn_mfma_f32_16x16x32_bf16(ap[s][0], vone, ol[s], 0, 0, 0);
      ol[s] = __builtin_amdgcn_mfma_f32_16x16x32_bf16(ap[s][1], vone, ol[s], 0, 0, 0);
    }

    // ---- V^T B-frags
    short8 bv[4][2];
#pragma unroll
    for (int t = 0; t < 4; ++t) {
      const unsigned short* vp = &vsb[(l15 + 16 * t) * 64];
      bv[t][0] = *(const short8*)(vp + ph0);
      bv[t][1] = *(const short8*)(vp + (ph0 ^ 32));
    }

    // ---- O += P V
#pragma unroll
    for (int t = 0; t < 4; ++t)
#pragma unroll
      for (int s = 0; s < 2; ++s) {
        o[s][t] = __builtin_amdgcn_mfma_f32_16x16x32_bf16(ap[s][0], bv[t][0], o[s][t], 0, 0, 0);
        o[s][t] = __builtin_amdgcn_mfma_f32_16x16x32_bf16(ap[s][1], bv[t][1], o[s][t], 0, 0, 0);
      }
  }

  // ---- epilogue: bf16 partial O + per-row l into slice si
  unsigned short* pb = pbuf + (size_t)si * OSLICE;
#pragma unroll
  for (int s = 0; s < 2; ++s) {
#pragma unroll
    for (int r = 0; r < 4; ++r) {
      const int trow = q0 + s * 64 + wave * 16 + quad * 4 + r;
      if (l15 == 0) lbuf[si * LPITCH + bh * SEQ_T + trow] = ol[s][r];
      const size_t base = ((size_t)bh * SEQ_T + trow) * DHEAD;
#pragma unroll
      for (int t = 0; t < 4; ++t) pb[base + l15 + 16 * t] = f2bf(o[s][t][r]);
    }
  }
}

// ---------------------------------------------------------------------------
// Kernel 3 (fused): attn_vec = (Sum_si O_si)/(Sum_si l_si); out =
// mean_h(attn_vec) @ W_out via MFMA vs Wob.  ns per row: qt = t>>7,
// ns = 1 + (qt>=4) + (qt>=12)  (uniform within a 16-row block).
// ---------------------------------------------------------------------------
__global__ __launch_bounds__(256) void out_merge(const unsigned short* __restrict__ pbuf,
                                                 const float* __restrict__ lbuf,
                                                 const unsigned short* __restrict__ Wob,
                                                 float* __restrict__ attnv,
                                                 float* __restrict__ out) {
  const int row0 = blockIdx.x * 16;   // global row = b*2048 + t
  const int tid = threadIdx.x;
  __shared__ float Ms[16][66];        // pitch 66: conflict-free frag reads

  {
    const int lr = tid >> 4;
    const int d0 = (tid & 15) * 4;
    const int row = row0 + lr;
    const int b = row >> 11;
    const int t = row & 2047;
    const int qt = t >> 7;
    const int ns = 1 + (qt >= 4 ? 1 : 0) + (qt >= 12 ? 1 : 0);
    float s0 = 0.f, s1 = 0.f, s2 = 0.f, s3 = 0.f;
#pragma unroll
    for (int hh = 0; hh < NHEAD; ++hh) {
      const size_t ridx = (size_t)(b * NHEAD + hh) * SEQ_T + t;
      float l = 0.f;
      float4 macc = {0.f, 0.f, 0.f, 0.f};
      const size_t idx = ridx * DHEAD + d0;
#pragma unroll
      for (int si = 0; si < 3; ++si) {
        if (si < ns) {
          l += lbuf[si * LPITCH + ridx];
          ushort4 A = *(const ushort4*)(pbuf + si * OSLICE + idx);
          macc.x += bf2f(A.x);
          macc.y += bf2f(A.y);
          macc.z += bf2f(A.z);
          macc.w += bf2f(A.w);
        }
      }
      const float inv = 1.0f / l;
      float4 mv;
      mv.x = macc.x * inv;
      mv.y = macc.y * inv;
      mv.z = macc.z * inv;
      mv.w = macc.w * inv;
      *(float4*)(attnv + idx) = mv;
      s0 += mv.x; s1 += mv.y; s2 += mv.z; s3 += mv.w;
    }
    Ms[lr][d0 + 0] = s0 * 0.125f;
    Ms[lr][d0 + 1] = s1 * 0.125f;
    Ms[lr][d0 + 2] = s2 * 0.125f;
    Ms[lr][d0 + 3] = s3 * 0.125f;
  }
  __syncthreads();

  // ---- out[16 rows][512] = Ms @ W_out via MFMA; wave w owns cols w*128..+128
  const int wv = tid >> 6;
  const int lane = tid & 63;
  const int quad = lane >> 4;
  const int l15 = lane & 15;

  short8 am[2];
  {
    union { unsigned short us[16]; short8 v[2]; } u;
#pragma unroll
    for (int j = 0; j < 8; ++j) {
      u.us[j] = f2bf(Ms[l15][quad * 8 + j]);
      u.us[8 + j] = f2bf(Ms[l15][32 + quad * 8 + j]);
    }
    am[0] = u.v[0];
    am[1] = u.v[1];
  }

#pragma unroll
  for (int nt = 0; nt < 8; ++nt) {
    const int n = wv * 128 + nt * 16 + l15;
    short8 b0 = *(const short8*)&Wob[(size_t)n * DHEAD + quad * 8];
    short8 b1 = *(const short8*)&Wob[(size_t)n * DHEAD + 32 + quad * 8];
    f32x4 c = (f32x4){0.f, 0.f, 0.f, 0.f};
    c = __builtin_amdgcn_mfma_f32_16x16x32_bf16(am[0], b0, c, 0, 0, 0);
    c = __builtin_amdgcn_mfma_f32_16x16x32_bf16(am[1], b1, c, 0, 0, 0);
#pragma unroll
    for (int r = 0; r < 4; ++r)
      out[(size_t)(row0 + quad * 4 + r) * HIDDEN + n] = c[r];
  }
}

// ---------------------------------------------------------------------------
extern "C" void kernel_launch(void* const* d_in, const int* in_sizes, int n_in,
                              void* d_out, int out_size, void* d_ws, size_t ws_size,
                              hipStream_t stream) {
  const float* x     = (const float*)d_in[0];   // (4,2048,512)
  const float* W_qkv = (const float*)d_in[1];   // (512,1088)
  const float* W_out = (const float*)d_in[2];   // (64,512)

  float* out      = (float*)d_out;                              // (4,2048,512)
  float* attn_vec = out + (size_t)BATCH * SEQ_T * HIDDEN;       // (4,8,2048,64)

  unsigned short* qkv  = (unsigned short*)d_ws;                 // 8192x1152 bf16 = 18.9 MB
  unsigned short* vt   = qkv + (size_t)NROWS * QPITCH;          // 1.0 MB bf16
  unsigned short* xb   = vt + (size_t)BATCH * DHEAD * SEQ_T;    // 8.4 MB bf16
  unsigned short* Wt   = xb + (size_t)NROWS * HIDDEN;           // 1152x512 bf16 = 1.2 MB
  unsigned short* pbuf = Wt + (size_t)QPITCH * HIDDEN;          // 3 x 8.4 MB bf16 partial O
  float*          lbuf = (float*)(pbuf + 3 * OSLICE);           // 3 x 0.26 MB
  unsigned short* Wob  = (unsigned short*)(lbuf + 3 * LPITCH);  // 512x64 bf16 = 64 KB

  prep<<<dim3(2048 + 136 + 8 + 8), 256, 0, stream>>>(x, W_qkv, W_out, xb, Wt, Wob);
  qkv_mfma<<<dim3(576), 256, 0, stream>>>(xb, Wt, qkv, vt);
  attn_pass<<<dim3(NBH, 32), 256, 0, stream>>>(qkv, vt, pbuf, lbuf);
  out_merge<<<dim3(512), 256, 0, stream>>>(pbuf, lbuf, Wob, attn_vec, out);
}

// Round 5
// 129.088 us; speedup vs baseline: 1.1482x; 1.0492x over previous
//
#include <hip/hip_runtime.h>
#include <hip/hip_bf16.h>

// Problem constants (reference: InterpretableMultiHeadAttention)
#define NHEAD  8
#define DHEAD  64
#define HIDDEN 512
#define SEQ_T  2048
#define BATCH  4
#define NQKV   1088          // (2*8+1)*64 true width
#define QPITCH 1152          // padded to 9*128 for BN=128 GEMM tiles
#define NT     32            // 2048/64 k-tiles
#define NROWS  (BATCH * SEQ_T)   // 8192
#define NBH    (BATCH * NHEAD)   // 32
#define LPITCH (NBH * SEQ_T)     // one lbuf slice
#define OSLICE ((size_t)NBH * SEQ_T * DHEAD)   // one pbuf slice
#define QSC    (0.125f * 1.44269504f)   // qk-scale * log2(e), folded into Q

typedef __attribute__((ext_vector_type(8))) short short8;   // 8 x bf16 (4 VGPRs)
typedef __attribute__((ext_vector_type(4))) float f32x4;

// round-to-nearest-even f32 -> bf16 (finite inputs only)
__device__ __forceinline__ unsigned short f2bf(float f) {
  unsigned int u = __float_as_uint(f);
  u += 0x7FFFu + ((u >> 16) & 1u);
  return (unsigned short)(u >> 16);
}
__device__ __forceinline__ float bf2f(unsigned short u) {
  return __uint_as_float((unsigned int)u << 16);
}

__device__ __forceinline__ void load_lds16(const unsigned short* g, unsigned short* l) {
  __builtin_amdgcn_global_load_lds((const __attribute__((address_space(1))) void*)g,
                                   (__attribute__((address_space(3))) void*)l, 16, 0, 0);
}

// ---------------------------------------------------------------------------
// Prep (fused): [0,2048): x fp32->bf16. [2048,2184): Wt transpose.
// [2184,2192): zero Wt pad rows 1088..1151. [2192,2200): W_out -> Wob[n][k]
// bf16 transpose (for out_merge MFMA).
// ---------------------------------------------------------------------------
__global__ __launch_bounds__(256) void prep(const float* __restrict__ x,
                                            const float* __restrict__ W,
                                            const float* __restrict__ Wout,
                                            unsigned short* __restrict__ xb,
                                            unsigned short* __restrict__ Wt,
                                            unsigned short* __restrict__ Wob) {
  const int bx = blockIdx.x;
  const int tid = threadIdx.x;
  if (bx < 2048) {
    const size_t i0 = ((size_t)bx * 256 + tid) * 8;
    float4 a = *(const float4*)(x + i0);
    float4 b = *(const float4*)(x + i0 + 4);
    ushort4 u0, u1;
    u0.x = f2bf(a.x); u0.y = f2bf(a.y); u0.z = f2bf(a.z); u0.w = f2bf(a.w);
    u1.x = f2bf(b.x); u1.y = f2bf(b.y); u1.z = f2bf(b.z); u1.w = f2bf(b.w);
    *(ushort4*)(xb + i0) = u0;
    *(ushort4*)(xb + i0 + 4) = u1;
    return;
  }
  if (bx >= 2184 && bx < 2192) {   // zero-fill Wt rows [1088,1152)
    const int z = bx - 2184;          // 0..7
    const size_t base = (size_t)NQKV * HIDDEN + ((size_t)z * 256 + tid) * 16;
    uint4 zero = {0u, 0u, 0u, 0u};
    *(uint4*)(Wt + base) = zero;
    *(uint4*)(Wt + base + 8) = zero;
    return;
  }
  if (bx >= 2192) {   // Wob[n][k] = bf16(W_out[k][n]), 8 blocks of 64 n-cols
    const int n0 = (bx - 2192) * 64;
    __shared__ float T[64 * 65];
#pragma unroll
    for (int i = 0; i < 4; ++i) {
      int f = tid + i * 256;
      int r = f >> 4;            // k row 0..63
      int c4 = (f & 15) * 4;     // n col within tile
      float4 v = *(const float4*)(Wout + (size_t)r * HIDDEN + n0 + c4);
      T[r * 65 + c4 + 0] = v.x;
      T[r * 65 + c4 + 1] = v.y;
      T[r * 65 + c4 + 2] = v.z;
      T[r * 65 + c4 + 3] = v.w;
    }
    __syncthreads();
#pragma unroll
    for (int i = 0; i < 4; ++i) {
      int f = tid + i * 256;
      int n = f >> 4;
      int k4 = (f & 15) * 4;
      ushort4 u;
      u.x = f2bf(T[(k4 + 0) * 65 + n]);
      u.y = f2bf(T[(k4 + 1) * 65 + n]);
      u.z = f2bf(T[(k4 + 2) * 65 + n]);
      u.w = f2bf(T[(k4 + 3) * 65 + n]);
      *(ushort4*)(Wob + (size_t)(n0 + n) * DHEAD + k4) = u;
    }
    return;
  }
  // Wt[n][k] = bf16(W[k][n]) via 64x64 LDS transpose
  const int idx = bx - 2048;          // 0..135
  const int n0 = (idx % 17) * 64;
  const int k0 = (idx / 17) * 64;
  __shared__ float T[64 * 65];
#pragma unroll
  for (int i = 0; i < 4; ++i) {
    int f = tid + i * 256;
    int r = f >> 4;
    int c4 = (f & 15) * 4;
    float4 v = *(const float4*)(W + (size_t)(k0 + r) * NQKV + n0 + c4);
    T[r * 65 + c4 + 0] = v.x;
    T[r * 65 + c4 + 1] = v.y;
    T[r * 65 + c4 + 2] = v.z;
    T[r * 65 + c4 + 3] = v.w;
  }
  __syncthreads();
#pragma unroll
  for (int i = 0; i < 4; ++i) {
    int f = tid + i * 256;
    int n = f >> 4;
    int k4 = (f & 15) * 4;
    ushort4 u;
    u.x = f2bf(T[(k4 + 0) * 65 + n]);
    u.y = f2bf(T[(k4 + 1) * 65 + n]);
    u.z = f2bf(T[(k4 + 2) * 65 + n]);
    u.w = f2bf(T[(k4 + 3) * 65 + n]);
    *(ushort4*)(Wt + (size_t)(n0 + n) * HIDDEN + k0 + k4) = u;
  }
}

// ---------------------------------------------------------------------------
// Kernel 1: qkv = xb @ Wt^T via bf16 MFMA.  BM=128, BN=128 (N padded 1152),
// BK=64.  XCD-aware 1D swizzle.  Q columns (bn<4) pre-scaled by QSC.
// bn==8 blocks hold V in accumulators -> fused V-transpose epilogue writes
// vt[b][d][k0+n] = V[b][k0+sigma(n)][d] directly.
// sigma(n) = 32*n5 + 16*n2 + 4*(n4n3) + (n1n0).
// ---------------------------------------------------------------------------
__global__ __launch_bounds__(256, 3) void qkv_mfma(const unsigned short* __restrict__ Xb,
                                                   const unsigned short* __restrict__ Wt,
                                                   unsigned short* __restrict__ Y,
                                                   unsigned short* __restrict__ vt) {
  __shared__ __align__(16) unsigned short SH[2 * 128 * 64];   // As | Bs (and V-stage alias)
  unsigned short* As = SH;
  unsigned short* Bs = SH + 128 * 64;
  const int L = blockIdx.x;       // 0..575
  const int slot = L >> 3;        // 0..71
  const int bm = (L & 7) * 8 + (slot & 7);   // 0..63
  const int bn = slot >> 3;                  // 0..8
  const int tid = threadIdx.x;
  const int wave = tid >> 6;
  const int lane = tid & 63;
  const int quad = lane >> 4;
  const int l15 = lane & 15;
  const int lrow = lane >> 3;
  const int lchunk = lane & 7;

  const unsigned short* xrow = Xb + (size_t)bm * 128 * HIDDEN;
  const unsigned short* wrow = Wt + (size_t)bn * 128 * HIDDEN;

  f32x4 acc[2][8];
#pragma unroll
  for (int mt = 0; mt < 2; ++mt)
#pragma unroll
    for (int nt = 0; nt < 8; ++nt) acc[mt][nt] = (f32x4){0.f, 0.f, 0.f, 0.f};

  for (int k0 = 0; k0 < HIDDEN; k0 += 64) {
    __syncthreads();
#pragma unroll
    for (int c = 0; c < 4; ++c) {
      int call = wave * 4 + c;
      int m = call * 8 + lrow;
      int clog = lchunk ^ lrow;
      load_lds16(xrow + (size_t)m * HIDDEN + k0 + clog * 8, &As[call * 512]);
      load_lds16(wrow + (size_t)m * HIDDEN + k0 + clog * 8, &Bs[call * 512]);
    }
    __syncthreads();

#pragma unroll
    for (int ks = 0; ks < 2; ++ks) {
      short8 a[2], b[8];
#pragma unroll
      for (int mt = 0; mt < 2; ++mt) {
        int m = wave * 32 + mt * 16 + l15;
        int phys = (ks * 4 + quad) ^ (l15 & 7);
        a[mt] = *(const short8*)&As[m * 64 + phys * 8];
      }
#pragma unroll
      for (int nt = 0; nt < 8; ++nt) {
        int n = nt * 16 + l15;
        int phys = (ks * 4 + quad) ^ (l15 & 7);
        b[nt] = *(const short8*)&Bs[n * 64 + phys * 8];
      }
#pragma unroll
      for (int mt = 0; mt < 2; ++mt)
#pragma unroll
        for (int nt = 0; nt < 8; ++nt)
          acc[mt][nt] = __builtin_amdgcn_mfma_f32_16x16x32_bf16(a[mt], b[nt], acc[mt][nt], 0, 0, 0);
    }
  }

  if (bn != 8) {
    const float qs = (bn < 4) ? QSC : 1.0f;   // pre-scale Q region (cols < 512)
#pragma unroll
    for (int mt = 0; mt < 2; ++mt)
#pragma unroll
      for (int r = 0; r < 4; ++r) {
        int row = bm * 128 + wave * 32 + mt * 16 + quad * 4 + r;
#pragma unroll
        for (int nt = 0; nt < 8; ++nt) {
          int col = bn * 128 + nt * 16 + l15;
          Y[(size_t)row * QPITCH + col] = f2bf(acc[mt][nt][r] * qs);
        }
      }
  } else {
    // ---- fused V-transpose: acc[mt][nt<4] = V[bm*128 + lr][d = nt*16+l15]
    __syncthreads();                       // all waves done reading As/Bs
    unsigned short* Vs = SH;               // [64 d][pitch 130] bf16 (16.6 KB)
#pragma unroll
    for (int mt = 0; mt < 2; ++mt)
#pragma unroll
      for (int nt = 0; nt < 4; ++nt)
#pragma unroll
        for (int r = 0; r < 4; ++r) {
          int lr = wave * 32 + mt * 16 + quad * 4 + r;
          int d = nt * 16 + l15;
          Vs[d * 130 + lr] = f2bf(acc[mt][nt][r]);
        }
    __syncthreads();
    const int bb = bm >> 4;                // batch
    const int t0 = (bm & 15) * 128;        // base t within batch
    const int half = lane >> 5;            // which 64-block of the 128 rows
    const int np = lane & 31;              // n-pair index (n = 2*np, 2*np+1)
    // sigma(2*np): bit0 of n is 0; sigma passes bit0 through -> pair stays adjacent
    const int s2 = ((np & 16) << 1) | ((np & 2) << 3) | (np & 12) | ((np & 1) << 1);
#pragma unroll
    for (int i = 0; i < 16; ++i) {
      int d = i * 4 + wave;
      unsigned int v = *(const unsigned int*)&Vs[d * 130 + half * 64 + s2];
      *(unsigned int*)&vt[((size_t)bb * DHEAD + d) * SEQ_T + t0 + half * 64 + 2 * np] = v;
    }
  }
}

// ---------------------------------------------------------------------------
// Kernel 2: flash attention pass, streaming softmax, k-split (fixed 2-way:
// kh=0 covers tiles [0,qt], kh=1 covers [qt+1,2qt+1]).  QBLK=128, (256,3),
// 12 waves/CU — the proven-best R2 configuration.
// Swapped-operand QK^T keeps P lane-local; P packed to bf16 A-frags in
// registers (vt's sigma order absorbs the kpos permutation).  l via MFMA vs
// all-ones.
// ---------------------------------------------------------------------------
__global__ __launch_bounds__(256, 3) void attn_pass(const unsigned short* __restrict__ qkv,
                                                    const unsigned short* __restrict__ vt,
                                                    unsigned short* __restrict__ pbuf,
                                                    float* __restrict__ lbuf) {
  const int bh = blockIdx.x;       // 0..31
  const int y = blockIdx.y;        // 0..31
  const int qt = 15 - (y >> 1);    // big tiles dispatched first
  const int kh = y & 1;
  const int si = kh;               // slice index
  const int b = bh >> 3;
  const int h = bh & 7;
  const int tid = threadIdx.x;
  const int wave = tid >> 6;
  const int lane = tid & 63;
  const int quad = lane >> 4;
  const int l15 = lane & 15;

  __shared__ __align__(16) unsigned short Ks[2][64 * 64];   // XOR-swizzled chunks
  __shared__ __align__(16) unsigned short Vts[2][64 * 64];  // XOR-swizzled chunks

  const unsigned short* bq = qkv + (size_t)b * SEQ_T * QPITCH;
  const unsigned short* bvt = vt + (size_t)b * DHEAD * SEQ_T;

  const int q0 = qt * 128;
  const int kbeg = kh ? (qt + 1) : 0;
  const int kend = kh ? (2 * qt + 1) : qt;  // inclusive

  // Q frags for both strips (pre-scaled by QSC in qkv_mfma); used as B operand
  short8 aq[2][2];
#pragma unroll
  for (int s = 0; s < 2; ++s) {
    const unsigned short* qp = bq + (size_t)(q0 + s * 64 + wave * 16 + l15) * QPITCH + h * 64 + quad * 8;
    aq[s][0] = *(const short8*)qp;
    aq[s][1] = *(const short8*)(qp + 32);
  }

  f32x4 o[2][4];
#pragma unroll
  for (int s = 0; s < 2; ++s)
#pragma unroll
    for (int t = 0; t < 4; ++t) o[s][t] = (f32x4){0.f, 0.f, 0.f, 0.f};
  f32x4 ol[2] = {(f32x4){0.f, 0.f, 0.f, 0.f}, (f32x4){0.f, 0.f, 0.f, 0.f}};
  const short8 vone = {(short)0x3F80, (short)0x3F80, (short)0x3F80, (short)0x3F80,
                       (short)0x3F80, (short)0x3F80, (short)0x3F80, (short)0x3F80};

  const int srow = tid >> 3;               // 0..31 staging row-within-call
  const int sch = (tid & 7) ^ (srow & 7);  // logical chunk to fetch
  const int ph0 = (quad ^ (l15 & 7)) * 8;  // frag-read physical chunk offset

  // prologue: stage first tile into buffer 0
#pragma unroll
  for (int c = 0; c < 2; ++c) {
    load_lds16(bq + (size_t)(kbeg * 64 + c * 32 + srow) * QPITCH + 512 + h * 64 + sch * 8,
               &Ks[0][c * 2048 + wave * 512]);
    load_lds16(bvt + (size_t)(c * 32 + srow) * SEQ_T + kbeg * 64 + sch * 8,
               &Vts[0][c * 2048 + wave * 512]);
  }

  for (int kt = kbeg; kt <= kend; ++kt) {
    const int k0 = kt * 64;
    const int cur = (kt - kbeg) & 1;
    __syncthreads();   // drains loads issued one full iteration ago
    if (kt < kend) {   // stage next tile into the other buffer (post-barrier)
      const int kn = (kt + 1) * 64;
      const int nxt = cur ^ 1;
#pragma unroll
      for (int c = 0; c < 2; ++c) {
        load_lds16(bq + (size_t)(kn + c * 32 + srow) * QPITCH + 512 + h * 64 + sch * 8,
                   &Ks[nxt][c * 2048 + wave * 512]);
        load_lds16(bvt + (size_t)(c * 32 + srow) * SEQ_T + kn + sch * 8,
                   &Vts[nxt][c * 2048 + wave * 512]);
      }
    }

    const unsigned short* ksb = Ks[cur];
    const unsigned short* vsb = Vts[cur];
    const bool needMask = (k0 + 63) > q0;

    // ---- K frags once (shared by both strips); used as A operand
    short8 bk[4][2];
#pragma unroll
    for (int t = 0; t < 4; ++t) {
      const unsigned short* kp = &ksb[(l15 + 16 * t) * 64];
      bk[t][0] = *(const short8*)(kp + ph0);
      bk[t][1] = *(const short8*)(kp + (ph0 ^ 32));
    }

    // ---- per strip: S^T = K Q^T -> exp2 -> in-register bf16 A-frag pack
    short8 ap[2][2];
#pragma unroll
    for (int s = 0; s < 2; ++s) {
      f32x4 pr[4];
#pragma unroll
      for (int t = 0; t < 4; ++t) {
        f32x4 sv = (f32x4){0.f, 0.f, 0.f, 0.f};
        sv = __builtin_amdgcn_mfma_f32_16x16x32_bf16(bk[t][0], aq[s][0], sv, 0, 0, 0);
        sv = __builtin_amdgcn_mfma_f32_16x16x32_bf16(bk[t][1], aq[s][1], sv, 0, 0, 0);
        pr[t] = sv;   // S^T: col l15 = q-row, row quad*4+r = kpos (in 16t block)
      }
      const int qrow = q0 + s * 64 + wave * 16 + l15;
#pragma unroll
      for (int t = 0; t < 4; ++t)
#pragma unroll
        for (int r = 0; r < 4; ++r) {
          float p = __builtin_amdgcn_exp2f(pr[t][r]);
          if (needMask)
            p = (k0 + 16 * t + 4 * quad + r <= qrow) ? p : 0.f;
          pr[t][r] = p;
        }
      // pack: A-frag half c, element j  <-  pr[2c + (j>>2)][j&3]
#pragma unroll
      for (int c = 0; c < 2; ++c) {
        union { unsigned int u[4]; short8 v; } pk;
        pk.u[0] = __builtin_amdgcn_perm(__float_as_uint(pr[2 * c][1]),
                                        __float_as_uint(pr[2 * c][0]), 0x07060302u);
        pk.u[1] = __builtin_amdgcn_perm(__float_as_uint(pr[2 * c][3]),
                                        __float_as_uint(pr[2 * c][2]), 0x07060302u);
        pk.u[2] = __builtin_amdgcn_perm(__float_as_uint(pr[2 * c + 1][1]),
                                        __float_as_uint(pr[2 * c + 1][0]), 0x07060302u);
        pk.u[3] = __builtin_amdgcn_perm(__float_as_uint(pr[2 * c + 1][3]),
                                        __float_as_uint(pr[2 * c + 1][2]), 0x07060302u);
        ap[s][c] = pk.v;
      }
      // l via MFMA against ones: C row quad*4+r holds sum_k P (dup over cols)
      ol[s] = __builtin_amdgcn_mfma_f32_16x16x32_bf16(ap[s][0], vone, ol[s], 0, 0, 0);
      ol[s] = __builtin_amdgcn_mfma_f32_16x16x32_bf16(ap[s][1], vone, ol[s], 0, 0, 0);
    }

    // ---- V^T B-frags
    short8 bv[4][2];
#pragma unroll
    for (int t = 0; t < 4; ++t) {
      const unsigned short* vp = &vsb[(l15 + 16 * t) * 64];
      bv[t][0] = *(const short8*)(vp + ph0);
      bv[t][1] = *(const short8*)(vp + (ph0 ^ 32));
    }

    // ---- O += P V
#pragma unroll
    for (int t = 0; t < 4; ++t)
#pragma unroll
      for (int s = 0; s < 2; ++s) {
        o[s][t] = __builtin_amdgcn_mfma_f32_16x16x32_bf16(ap[s][0], bv[t][0], o[s][t], 0, 0, 0);
        o[s][t] = __builtin_amdgcn_mfma_f32_16x16x32_bf16(ap[s][1], bv[t][1], o[s][t], 0, 0, 0);
      }
  }

  // ---- epilogue: bf16 partial O + per-row l into slice si
  unsigned short* pb = pbuf + (size_t)si * OSLICE;
#pragma unroll
  for (int s = 0; s < 2; ++s) {
#pragma unroll
    for (int r = 0; r < 4; ++r) {
      const int trow = q0 + s * 64 + wave * 16 + quad * 4 + r;
      if (l15 == 0) lbuf[si * LPITCH + bh * SEQ_T + trow] = ol[s][r];
      const size_t base = ((size_t)bh * SEQ_T + trow) * DHEAD;
#pragma unroll
      for (int t = 0; t < 4; ++t) pb[base + l15 + 16 * t] = f2bf(o[s][t][r]);
    }
  }
}

// ---------------------------------------------------------------------------
// Kernel 3 (fused): attn_vec = (O0+O1)/(l0+l1); out = mean_h(attn_vec) @ W_out
// via MFMA vs Wob (prep-transposed W_out).
// ---------------------------------------------------------------------------
__global__ __launch_bounds__(256) void out_merge(const unsigned short* __restrict__ pbuf,
                                                 const float* __restrict__ lbuf,
                                                 const unsigned short* __restrict__ Wob,
                                                 float* __restrict__ attnv,
                                                 float* __restrict__ out) {
  const int row0 = blockIdx.x * 16;   // global row = b*2048 + t
  const int tid = threadIdx.x;
  __shared__ float Ms[16][66];        // pitch 66: conflict-free frag reads

  {
    const int lr = tid >> 4;
    const int d0 = (tid & 15) * 4;
    const int row = row0 + lr;
    const int b = row >> 11;
    const int t = row & 2047;
    float s0 = 0.f, s1 = 0.f, s2 = 0.f, s3 = 0.f;
#pragma unroll
    for (int hh = 0; hh < NHEAD; ++hh) {
      const size_t ridx = (size_t)(b * NHEAD + hh) * SEQ_T + t;
      const float inv = 1.0f / (lbuf[ridx] + lbuf[LPITCH + ridx]);
      const size_t idx = ridx * DHEAD + d0;
      ushort4 A = *(const ushort4*)(pbuf + idx);
      ushort4 B = *(const ushort4*)(pbuf + OSLICE + idx);
      float4 m;
      m.x = (bf2f(A.x) + bf2f(B.x)) * inv;
      m.y = (bf2f(A.y) + bf2f(B.y)) * inv;
      m.z = (bf2f(A.z) + bf2f(B.z)) * inv;
      m.w = (bf2f(A.w) + bf2f(B.w)) * inv;
      *(float4*)(attnv + idx) = m;
      s0 += m.x; s1 += m.y; s2 += m.z; s3 += m.w;
    }
    Ms[lr][d0 + 0] = s0 * 0.125f;
    Ms[lr][d0 + 1] = s1 * 0.125f;
    Ms[lr][d0 + 2] = s2 * 0.125f;
    Ms[lr][d0 + 3] = s3 * 0.125f;
  }
  __syncthreads();

  // ---- out[16 rows][512] = Ms @ W_out via MFMA; wave w owns cols w*128..+128
  const int wv = tid >> 6;
  const int lane = tid & 63;
  const int quad = lane >> 4;
  const int l15 = lane & 15;

  short8 am[2];
  {
    union { unsigned short us[16]; short8 v[2]; } u;
#pragma unroll
    for (int j = 0; j < 8; ++j) {
      u.us[j] = f2bf(Ms[l15][quad * 8 + j]);
      u.us[8 + j] = f2bf(Ms[l15][32 + quad * 8 + j]);
    }
    am[0] = u.v[0];
    am[1] = u.v[1];
  }

#pragma unroll
  for (int nt = 0; nt < 8; ++nt) {
    const int n = wv * 128 + nt * 16 + l15;
    short8 b0 = *(const short8*)&Wob[(size_t)n * DHEAD + quad * 8];
    short8 b1 = *(const short8*)&Wob[(size_t)n * DHEAD + 32 + quad * 8];
    f32x4 c = (f32x4){0.f, 0.f, 0.f, 0.f};
    c = __builtin_amdgcn_mfma_f32_16x16x32_bf16(am[0], b0, c, 0, 0, 0);
    c = __builtin_amdgcn_mfma_f32_16x16x32_bf16(am[1], b1, c, 0, 0, 0);
#pragma unroll
    for (int r = 0; r < 4; ++r)
      out[(size_t)(row0 + quad * 4 + r) * HIDDEN + n] = c[r];
  }
}

// ---------------------------------------------------------------------------
extern "C" void kernel_launch(void* const* d_in, const int* in_sizes, int n_in,
                              void* d_out, int out_size, void* d_ws, size_t ws_size,
                              hipStream_t stream) {
  const float* x     = (const float*)d_in[0];   // (4,2048,512)
  const float* W_qkv = (const float*)d_in[1];   // (512,1088)
  const float* W_out = (const float*)d_in[2];   // (64,512)

  float* out      = (float*)d_out;                              // (4,2048,512)
  float* attn_vec = out + (size_t)BATCH * SEQ_T * HIDDEN;       // (4,8,2048,64)

  unsigned short* qkv  = (unsigned short*)d_ws;                 // 8192x1152 bf16 = 18.9 MB
  unsigned short* vt   = qkv + (size_t)NROWS * QPITCH;          // 1.0 MB bf16
  unsigned short* xb   = vt + (size_t)BATCH * DHEAD * SEQ_T;    // 8.4 MB bf16
  unsigned short* Wt   = xb + (size_t)NROWS * HIDDEN;           // 1152x512 bf16 = 1.2 MB
  unsigned short* pbuf = Wt + (size_t)QPITCH * HIDDEN;          // 2 x 8.4 MB bf16 partial O
  float*          lbuf = (float*)(pbuf + 2 * OSLICE);           // 2 x 0.26 MB
  unsigned short* Wob  = (unsigned short*)(lbuf + 2 * LPITCH);  // 512x64 bf16 = 64 KB

  prep<<<dim3(2048 + 136 + 8 + 8), 256, 0, stream>>>(x, W_qkv, W_out, xb, Wt, Wob);
  qkv_mfma<<<dim3(576), 256, 0, stream>>>(xb, Wt, qkv, vt);
  attn_pass<<<dim3(NBH, 32), 256, 0, stream>>>(qkv, vt, pbuf, lbuf);
  out_merge<<<dim3(512), 256, 0, stream>>>(pbuf, lbuf, Wob, attn_vec, out);
}